// Round 11
// baseline (538.885 us; speedup 1.0000x reference)
//
#include <hip/hip_runtime.h>
#include <hip/hip_fp16.h>
#include <hip/hip_cooperative_groups.h>
#include <math.h>

#define D 128
#define NSL 128         // edge slices per histogram (= blocks per hist array)
#define PBU 25088       // packed u8 counters (uints) -> supports N <= 100352
#define GRID 256
#define BLK 1024

namespace cg = cooperative_groups;

typedef _Float16 half8 __attribute__((ext_vector_type(8)));
typedef float f32x4 __attribute__((ext_vector_type(4)));

__device__ inline uint pack_f16x2(float a, float b) {
  __half2 h = __floats2half2_rn(a, b);
  return *reinterpret_cast<uint*>(&h);
}
__device__ inline float2 unpack_f16x2(uint p) {
  __half2 h = *reinterpret_cast<__half2*>(&p);
  return __half22float2(h);
}
__device__ inline uint mdiv40(uint x, uint M) {  // x / d with M = ceil(2^40/d)
  return (uint)(((unsigned long long)x * M) >> 40);
}

struct MegaArgs {
  const float* x; const int* esrc; const int* edst;
  const float* W0; const float* b0; const float* W1; const float* b1;
  const float* W2; const float* b2;
  const float* g0; const float* be0; const float* mu0; const float* vr0;
  const float* g1; const float* be1; const float* mu1; const float* vr1;
  uint* pd; uint* ps; uchar* rank8;
  ushort* Wt; float* CA; float* CB;
  float* ns; float* nd; int* totd; int* csum; int* rofs;
  int* csr; uint* hs16; uint* bufA; float* outF;
  int N, E, SB, nch2; uint Msb;
};

// ---- GEMM wave-tile (f16 input). Low-VGPR: per-nt accumulators, store immediately. ----
__device__ inline void gemm_wave_f16(const ushort* __restrict__ A,
                                     const ushort* __restrict__ Wt,
                                     ushort* __restrict__ out, int M, int w, int lane) {
  const int m0 = w * 32;
  if (m0 >= M) return;
  const int lr = lane & 15;
  const int kg = (lane >> 4) * 8;
  half8 hf[2][4];
  const half8 hz = {};
#pragma unroll
  for (int mt = 0; mt < 2; ++mt) {
    const int row = m0 + mt * 16 + lr;
    const bool ok = row < M;
#pragma unroll
    for (int kt = 0; kt < 4; ++kt)
      hf[mt][kt] = ok ? *reinterpret_cast<const half8*>(A + (size_t)row * D + kt * 32 + kg) : hz;
  }
  const int no = (lane >> 4) * 4;
#pragma unroll
  for (int nt = 0; nt < 8; ++nt) {
    f32x4 a0 = (f32x4)(0.f), a1 = (f32x4)(0.f);
    const ushort* wb = Wt + (size_t)(nt * 16 + lr) * D + kg;
#pragma unroll
    for (int kt = 0; kt < 4; ++kt) {
      half8 wf = *reinterpret_cast<const half8*>(wb + kt * 32);
      a0 = __builtin_amdgcn_mfma_f32_16x16x32_f16(wf, hf[0][kt], a0, 0, 0, 0);
      a1 = __builtin_amdgcn_mfma_f32_16x16x32_f16(wf, hf[1][kt], a1, 0, 0, 0);
    }
    const int r0 = m0 + lr, r1 = m0 + 16 + lr;
    if (r0 < M) {
      uint2 u; u.x = pack_f16x2(a0[0], a0[1]); u.y = pack_f16x2(a0[2], a0[3]);
      *reinterpret_cast<uint2*>(out + (size_t)r0 * D + nt * 16 + no) = u;
    }
    if (r1 < M) {
      uint2 u; u.x = pack_f16x2(a1[0], a1[1]); u.y = pack_f16x2(a1[2], a1[3]);
      *reinterpret_cast<uint2*>(out + (size_t)r1 * D + nt * 16 + no) = u;
    }
  }
}

// ---- GEMM wave-tile (f32 input, scaled by ns) for layer 0. ----
__device__ inline void gemm_wave_f32(const float* __restrict__ X,
                                     const ushort* __restrict__ Wt,
                                     const float* __restrict__ ns,
                                     ushort* __restrict__ out, int M, int w, int lane) {
  const int m0 = w * 32;
  if (m0 >= M) return;
  const int lr = lane & 15;
  const int kg = (lane >> 4) * 8;
  half8 hf[2][4];
  const half8 hz = {};
#pragma unroll
  for (int mt = 0; mt < 2; ++mt) {
    const int row = m0 + mt * 16 + lr;
    if (row < M) {
      const float s = ns[row];
#pragma unroll
      for (int kt = 0; kt < 4; ++kt) {
        const float4 a = *reinterpret_cast<const float4*>(X + (size_t)row * D + kt * 32 + kg);
        const float4 b = *reinterpret_cast<const float4*>(X + (size_t)row * D + kt * 32 + kg + 4);
        half8 hv;
        hv[0] = (_Float16)(a.x * s); hv[1] = (_Float16)(a.y * s);
        hv[2] = (_Float16)(a.z * s); hv[3] = (_Float16)(a.w * s);
        hv[4] = (_Float16)(b.x * s); hv[5] = (_Float16)(b.y * s);
        hv[6] = (_Float16)(b.z * s); hv[7] = (_Float16)(b.w * s);
        hf[mt][kt] = hv;
      }
    } else {
#pragma unroll
      for (int kt = 0; kt < 4; ++kt) hf[mt][kt] = hz;
    }
  }
  const int no = (lane >> 4) * 4;
#pragma unroll
  for (int nt = 0; nt < 8; ++nt) {
    f32x4 a0 = (f32x4)(0.f), a1 = (f32x4)(0.f);
    const ushort* wb = Wt + (size_t)(nt * 16 + lr) * D + kg;
#pragma unroll
    for (int kt = 0; kt < 4; ++kt) {
      half8 wf = *reinterpret_cast<const half8*>(wb + kt * 32);
      a0 = __builtin_amdgcn_mfma_f32_16x16x32_f16(wf, hf[0][kt], a0, 0, 0, 0);
      a1 = __builtin_amdgcn_mfma_f32_16x16x32_f16(wf, hf[1][kt], a1, 0, 0, 0);
    }
    const int r0 = m0 + lr, r1 = m0 + 16 + lr;
    if (r0 < M) {
      uint2 u; u.x = pack_f16x2(a0[0], a0[1]); u.y = pack_f16x2(a0[2], a0[3]);
      *reinterpret_cast<uint2*>(out + (size_t)r0 * D + nt * 16 + no) = u;
    }
    if (r1 < M) {
      uint2 u; u.x = pack_f16x2(a1[0], a1[1]); u.y = pack_f16x2(a1[2], a1[3]);
      *reinterpret_cast<uint2*>(out + (size_t)r1 * D + nt * 16 + no) = u;
    }
  }
}

// ---- SpMM phase: 16-lane group per dst row, grid-stride, 4-deep clamped gather. ----
__device__ inline void spmm_phase(const uint* __restrict__ hs,
                                  const int* __restrict__ csr,
                                  const int* __restrict__ rofs,
                                  const float* __restrict__ nd,
                                  const float* __restrict__ ns,
                                  const float* __restrict__ CA,
                                  const float* __restrict__ CB,
                                  float* __restrict__ outf,
                                  uint* __restrict__ hnext,
                                  int N, int gid, int lane, int last) {
  const int c16 = lane & 15;
  const int gb = lane & ~15;
  for (int d = gid >> 4; d < N; d += (GRID * BLK) >> 4) {
    const int beg = rofs[d], end = rofs[d + 1];
    float acc[8];
#pragma unroll
    for (int j = 0; j < 8; ++j) acc[j] = 0.f;
    for (int base = beg; base < end; base += 16) {
      const int len = min(16, end - base);
      const int idx = csr[min(base + c16, end - 1)];
#pragma unroll 1
      for (int j = 0; j < len; j += 4) {
        const int l1 = min(j + 1, len - 1), l2 = min(j + 2, len - 1), l3 = min(j + 3, len - 1);
        const int s0 = __shfl(idx, gb + j);
        const int s1 = __shfl(idx, gb + l1);
        const int s2 = __shfl(idx, gb + l2);
        const int s3 = __shfl(idx, gb + l3);
        const float w1 = (j + 1 < len) ? 1.f : 0.f;
        const float w2 = (j + 2 < len) ? 1.f : 0.f;
        const float w3 = (j + 3 < len) ? 1.f : 0.f;
        const uint4 v0 = *reinterpret_cast<const uint4*>(hs + (size_t)s0 * 64 + c16 * 4);
        const uint4 v1 = *reinterpret_cast<const uint4*>(hs + (size_t)s1 * 64 + c16 * 4);
        const uint4 v2 = *reinterpret_cast<const uint4*>(hs + (size_t)s2 * 64 + c16 * 4);
        const uint4 v3 = *reinterpret_cast<const uint4*>(hs + (size_t)s3 * 64 + c16 * 4);
#pragma unroll
        for (int q = 0; q < 4; ++q) {
          const float2 a0 = unpack_f16x2((&v0.x)[q]);
          const float2 a1 = unpack_f16x2((&v1.x)[q]);
          const float2 a2 = unpack_f16x2((&v2.x)[q]);
          const float2 a3 = unpack_f16x2((&v3.x)[q]);
          acc[q * 2]     += a0.x;
          acc[q * 2 + 1] += a0.y;
          acc[q * 2]     = fmaf(a1.x, w1, acc[q * 2]);
          acc[q * 2 + 1] = fmaf(a1.y, w1, acc[q * 2 + 1]);
          acc[q * 2]     = fmaf(a2.x, w2, acc[q * 2]);
          acc[q * 2 + 1] = fmaf(a2.y, w2, acc[q * 2 + 1]);
          acc[q * 2]     = fmaf(a3.x, w3, acc[q * 2]);
          acc[q * 2 + 1] = fmaf(a3.y, w3, acc[q * 2 + 1]);
        }
      }
    }
    const float ndv = nd[d];
    const float4 ca0 = *reinterpret_cast<const float4*>(CA + c16 * 8);
    const float4 ca1 = *reinterpret_cast<const float4*>(CA + c16 * 8 + 4);
    const float4 cb0 = *reinterpret_cast<const float4*>(CB + c16 * 8);
    const float4 cb1 = *reinterpret_cast<const float4*>(CB + c16 * 8 + 4);
    float r[8];
    r[0] = acc[0] * ndv * ca0.x + cb0.x;
    r[1] = acc[1] * ndv * ca0.y + cb0.y;
    r[2] = acc[2] * ndv * ca0.z + cb0.z;
    r[3] = acc[3] * ndv * ca0.w + cb0.w;
    r[4] = acc[4] * ndv * ca1.x + cb1.x;
    r[5] = acc[5] * ndv * ca1.y + cb1.y;
    r[6] = acc[6] * ndv * ca1.z + cb1.z;
    r[7] = acc[7] * ndv * ca1.w + cb1.w;
    if (!last) {
      const float s = ns[d];
#pragma unroll
      for (int j = 0; j < 8; ++j) r[j] = fmaxf(r[j], 0.f) * s;
      uint4 u;
      u.x = pack_f16x2(r[0], r[1]);
      u.y = pack_f16x2(r[2], r[3]);
      u.z = pack_f16x2(r[4], r[5]);
      u.w = pack_f16x2(r[6], r[7]);
      *reinterpret_cast<uint4*>(hnext + (size_t)d * 64 + c16 * 4) = u;
    } else {
      float4 o0 = make_float4(r[0], r[1], r[2], r[3]);
      float4 o1 = make_float4(r[4], r[5], r[6], r[7]);
      *reinterpret_cast<float4*>(outf + (size_t)d * D + c16 * 8) = o0;
      *reinterpret_cast<float4*>(outf + (size_t)d * D + c16 * 8 + 4) = o1;
    }
  }
}

// ---------------- the mega kernel ----------------

__global__ __launch_bounds__(BLK) void k_mega(MegaArgs a) {
  __shared__ uint h[PBU];   // ~98 KB -> 1 block/CU
  cg::grid_group grid = cg::this_grid();
  const int t = threadIdx.x;
  const int bid = blockIdx.x;
  const int gid = bid * BLK + t;
  const int lane = t & 63;
  const int wid = gid >> 6;

  // ---- Phase 0: histograms (+rank), Wt transpose, CA/CB ----
  for (int j = t; j < PBU; j += BLK) h[j] = 0u;
  __syncthreads();
  {
    const int sl = (bid < NSL) ? bid : bid - NSL;
    const int i0 = sl * a.SB, i1 = min(i0 + a.SB, a.E);
    if (bid < NSL) {
      for (int i = i0 + t; i < i1; i += BLK) {
        const int d = a.edst[i];
        const uint sh = (uint)(d & 3) * 8u;
        const uint old = atomicAdd(&h[d >> 2], 1u << sh);
        a.rank8[i] = (uchar)((old >> sh) & 0xffu);
      }
    } else {
      for (int i = i0 + t; i < i1; i += BLK) {
        const int s = a.esrc[i];
        atomicAdd(&h[s >> 2], 1u << ((uint)(s & 3) * 8u));
      }
    }
  }
  __syncthreads();
  {
    uint* p = ((bid < NSL) ? a.pd : a.ps) + (size_t)((bid < NSL) ? bid : bid - NSL) * PBU;
    for (int j = t; j < PBU; j += BLK) p[j] = h[j];
  }
  if (gid < 3 * D * D) {
    const int li = gid;
    const int l = li >> 14;
    const int i = li & 16383;
    const int n = i >> 7, k = i & 127;
    const float* W = (l == 0) ? a.W0 : ((l == 1) ? a.W1 : a.W2);
    a.Wt[li] = __half_as_ushort(__float2half_rn(W[k * D + n]));
  } else if (gid < 3 * D * D + D) {
    const int c = gid - 3 * D * D;
    float A0 = a.g0[c] * rsqrtf(a.vr0[c] + 1e-5f);
    a.CA[c] = A0;
    a.CB[c] = (a.b0[c] - a.mu0[c]) * A0 + a.be0[c];
    float A1 = a.g1[c] * rsqrtf(a.vr1[c] + 1e-5f);
    a.CA[D + c] = A1;
    a.CB[D + c] = (a.b1[c] - a.mu1[c]) * A1 + a.be1[c];
    a.CA[2 * D + c] = 1.f;
    a.CB[2 * D + c] = a.b2[c];
  }
  grid.sync();

  // ---- Phase 1: wave-per-256-node-chunk reduce + in-place u8 prefix + chunk sums ----
  if (wid < a.nch2) {
    const int j = wid * 64 + lane;       // packed uint (4 nodes); j < PBU guaranteed
    uint r0 = 0, r1 = 0, r2 = 0, r3 = 0, s0 = 0, s1 = 0, s2 = 0, s3 = 0;
#pragma unroll 8
    for (int sl = 0; sl < NSL; ++sl) {
      uint* pp = a.pd + (size_t)sl * PBU + j;
      const uint v = *pp;
      *pp = r0 | (r1 << 8) | (r2 << 16) | (r3 << 24);
      r0 += v & 0xffu; r1 += (v >> 8) & 0xffu; r2 += (v >> 16) & 0xffu; r3 += (v >> 24) & 0xffu;
      const uint w = a.ps[(size_t)sl * PBU + j];
      s0 += w & 0xffu; s1 += (w >> 8) & 0xffu; s2 += (w >> 16) & 0xffu; s3 += (w >> 24) & 0xffu;
    }
    const uint rr[4] = {r0, r1, r2, r3};
    const uint ss[4] = {s0, s1, s2, s3};
    const int n0 = j * 4;
    int tot = 0;
#pragma unroll
    for (int k = 0; k < 4; ++k) {
      if (n0 + k < a.N) {
        a.totd[n0 + k] = (int)rr[k];
        a.nd[n0 + k] = rsqrtf((float)max(rr[k], 1u));
        a.ns[n0 + k] = rsqrtf((float)max(ss[k], 1u));
        tot += (int)rr[k];
      }
    }
#pragma unroll
    for (int off = 32; off >= 1; off >>= 1) tot += __shfl_xor(tot, off);
    if (lane == 0) a.csum[wid] = tot;
  }
  grid.sync();

  // ---- Phase 2: exclusive scan of chunk sums by one wave ----
  if (bid == 0 && t < 64) {
    int run = 0;
    for (int b0 = 0; b0 < a.nch2; b0 += 64) {
      const int idx = b0 + t;
      int v = (idx < a.nch2) ? a.csum[idx] : 0;
      int sc = v;
#pragma unroll
      for (int off = 1; off < 64; off <<= 1) {
        int u = __shfl_up(sc, off);
        if (t >= off) sc += u;
      }
      if (idx < a.nch2) a.csum[idx] = run + sc - v;
      run += __shfl(sc, 63);
    }
    if (t == 0) a.rofs[a.N] = run;
  }
  grid.sync();

  // ---- Phase 3: per-node rofs (wave-local scan per 256-node chunk) ----
  if (wid < a.nch2) {
    const int base = wid * 256 + lane * 4;
    int v[4]; int s = 0;
#pragma unroll
    for (int i = 0; i < 4; ++i) { v[i] = (base + i < a.N) ? a.totd[base + i] : 0; s += v[i]; }
    int sc = s;
#pragma unroll
    for (int off = 1; off < 64; off <<= 1) {
      int u = __shfl_up(sc, off);
      if (lane >= off) sc += u;
    }
    int o = a.csum[wid] + sc - s;
#pragma unroll
    for (int i = 0; i < 4; ++i) {
      if (base + i < a.N) { a.rofs[base + i] = o; o += v[i]; }
    }
  }
  grid.sync();

  // ---- Phase 4: scatter (all threads) + Phase 5: layer-0 GEMM (independent) ----
  for (int i = gid; i < a.E; i += GRID * BLK) {
    const int d = a.edst[i];
    const uint sl = mdiv40((uint)i, a.Msb);
    const uint pk = a.pd[(size_t)sl * PBU + (d >> 2)];
    const uint pfx = (pk >> ((uint)(d & 3) * 8u)) & 0xffu;
    a.csr[a.rofs[d] + (int)pfx + (int)a.rank8[i]] = a.esrc[i];
  }
  gemm_wave_f32(a.x, a.Wt, a.ns, (ushort*)a.hs16, a.N, wid, lane);
  grid.sync();

  // ---- Phase 6: spmm L0 -> bufA (f16) ----
  spmm_phase(a.hs16, a.csr, a.rofs, a.nd, a.ns, a.CA, a.CB, nullptr, a.bufA, a.N, gid, lane, 0);
  grid.sync();

  // ---- Phase 7: gemm L1 ----
  gemm_wave_f16((const ushort*)a.bufA, a.Wt + 16384, (ushort*)a.hs16, a.N, wid, lane);
  grid.sync();

  // ---- Phase 8: spmm L1 -> bufA ----
  spmm_phase(a.hs16, a.csr, a.rofs, a.nd, a.ns, a.CA + D, a.CB + D, nullptr, a.bufA, a.N,
             gid, lane, 0);
  grid.sync();

  // ---- Phase 9: gemm L2 ----
  gemm_wave_f16((const ushort*)a.bufA, a.Wt + 32768, (ushort*)a.hs16, a.N, wid, lane);
  grid.sync();

  // ---- Phase 10: spmm L2 -> final fp32 out ----
  spmm_phase(a.hs16, a.csr, a.rofs, a.nd, a.ns, a.CA + 2 * D, a.CB + 2 * D, a.outF, nullptr,
             a.N, gid, lane, 1);
}

// ---------------- launch ----------------

extern "C" void kernel_launch(void* const* d_in, const int* in_sizes, int n_in,
                              void* d_out, int out_size, void* d_ws, size_t ws_size,
                              hipStream_t stream) {
  const int N = in_sizes[0] / D;
  const int E = in_sizes[1];
  const int SB = (E + NSL - 1) / NSL;
  const uint Msb = (uint)(((1ULL << 40) + (unsigned long long)SB - 1) / (unsigned long long)SB);

  char* p = (char*)d_ws;
  auto carve = [&](size_t bytes) {
    char* r = p;
    p += (bytes + 255) & ~(size_t)255;
    return (void*)r;
  };
  uint* hs16 = (uint*)carve((size_t)N * 64 * 4);
  ushort* Wt = (ushort*)carve((size_t)3 * D * D * 2);
  float* CA = (float*)carve((size_t)3 * D * 4);
  float* CB = (float*)carve((size_t)3 * D * 4);
  float* ns = (float*)carve((size_t)N * 4);
  float* nd = (float*)carve((size_t)N * 4);
  uint* pd = (uint*)carve((size_t)NSL * PBU * 4);
  uint* ps = (uint*)carve((size_t)NSL * PBU * 4);
  uchar* rank8 = (uchar*)carve((size_t)E);
  int* totd = (int*)carve((size_t)N * 4);
  int* rofs = (int*)carve((size_t)(N + 1) * 4);
  const int nch2 = (N + 255) / 256;
  int* csum = (int*)carve((size_t)nch2 * 4);
  int* csr = (int*)carve((size_t)E * 4);

  MegaArgs args;
  args.x = (const float*)d_in[0];
  args.esrc = (const int*)d_in[1];
  args.edst = (const int*)d_in[2];
  args.W0 = (const float*)d_in[3];  args.b0 = (const float*)d_in[4];
  args.W1 = (const float*)d_in[5];  args.b1 = (const float*)d_in[6];
  args.W2 = (const float*)d_in[7];  args.b2 = (const float*)d_in[8];
  args.g0 = (const float*)d_in[9];  args.be0 = (const float*)d_in[10];
  args.mu0 = (const float*)d_in[11]; args.vr0 = (const float*)d_in[12];
  args.g1 = (const float*)d_in[13]; args.be1 = (const float*)d_in[14];
  args.mu1 = (const float*)d_in[15]; args.vr1 = (const float*)d_in[16];
  args.pd = pd; args.ps = ps; args.rank8 = rank8;
  args.Wt = Wt; args.CA = CA; args.CB = CB;
  args.ns = ns; args.nd = nd; args.totd = totd; args.csum = csum; args.rofs = rofs;
  args.csr = csr; args.hs16 = hs16;
  args.bufA = (uint*)d_out;     // inter-layer f16 ping buffer (fully rewritten)
  args.outF = (float*)d_out;    // final fp32 output
  args.N = N; args.E = E; args.SB = SB; args.nch2 = nch2; args.Msb = Msb;

  void* kp[] = {&args};
  hipLaunchCooperativeKernel((const void*)k_mega, dim3(GRID), dim3(BLK), kp, 0, stream);
}

// Round 12
// 251.738 us; speedup vs baseline: 2.1407x; 2.1407x over previous
//
#include <hip/hip_runtime.h>
#include <hip/hip_fp16.h>
#include <math.h>

#define D 128
#define NSL 32          // edge slices
#define PBU 25088       // packed u8 counters (uints) -> supports N <= 100352

typedef _Float16 half8 __attribute__((ext_vector_type(8)));
typedef float f32x4 __attribute__((ext_vector_type(4)));

__device__ inline uint pack_f16x2(float a, float b) {
  __half2 h = __floats2half2_rn(a, b);
  return *reinterpret_cast<uint*>(&h);
}
__device__ inline float2 unpack_f16x2(uint p) {
  __half2 h = *reinterpret_cast<__half2*>(&p);
  return __half22float2(h);
}
__device__ inline uint mdiv40(uint x, uint M) {  // x / d with M = ceil(2^40/d)
  return (uint)(((unsigned long long)x * M) >> 40);
}

// ---------------- build1: fused {dst-hist+rank, src-hist, Wt transpose, CA/CB} ----------
// blocks 0..31: dst histogram slice; 32..63: src histogram slice; 64..111: Wt; 112: CA/CB.

__global__ __launch_bounds__(1024) void k_build1(const int* __restrict__ esrc,
                                                 const int* __restrict__ edst,
                                                 const float* __restrict__ W0,
                                                 const float* __restrict__ W1,
                                                 const float* __restrict__ W2,
                                                 const float* __restrict__ b0,
                                                 const float* __restrict__ b1,
                                                 const float* __restrict__ b2,
                                                 const float* __restrict__ g0,
                                                 const float* __restrict__ be0,
                                                 const float* __restrict__ mu0,
                                                 const float* __restrict__ vr0,
                                                 const float* __restrict__ g1,
                                                 const float* __restrict__ be1,
                                                 const float* __restrict__ mu1,
                                                 const float* __restrict__ vr1,
                                                 uint* __restrict__ pd,
                                                 uint* __restrict__ ps,
                                                 uchar* __restrict__ rank8,
                                                 ushort* __restrict__ Wt,
                                                 float* __restrict__ CA,
                                                 float* __restrict__ CB,
                                                 int E, int SB) {
  __shared__ uint h[PBU];   // ~98 KB static LDS (hist blocks only)
  const int b = blockIdx.x;
  const int t = threadIdx.x;
  if (b < 32) {             // ---- dst histogram + rank record
    for (int j = t; j < PBU; j += 1024) h[j] = 0u;
    __syncthreads();
    const int i0 = b * SB, i1 = min(i0 + SB, E);
    for (int i = i0 + t; i < i1; i += 1024) {
      const int d = edst[i];
      const uint sh = (uint)(d & 3) * 8u;
      const uint old = atomicAdd(&h[d >> 2], 1u << sh);
      rank8[i] = (uchar)((old >> sh) & 0xffu);
    }
    __syncthreads();
    uint* p = pd + (size_t)b * PBU;
    for (int j = t; j < PBU; j += 1024) p[j] = h[j];
  } else if (b < 64) {      // ---- src histogram (counts only)
    const int sl = b - 32;
    for (int j = t; j < PBU; j += 1024) h[j] = 0u;
    __syncthreads();
    const int i0 = sl * SB, i1 = min(i0 + SB, E);
    for (int i = i0 + t; i < i1; i += 1024) {
      const int s = esrc[i];
      atomicAdd(&h[s >> 2], 1u << ((uint)(s & 3) * 8u));
    }
    __syncthreads();
    uint* p = ps + (size_t)sl * PBU;
    for (int j = t; j < PBU; j += 1024) p[j] = h[j];
  } else if (b < 112) {     // ---- Wt[l][n][k] = f16(W_l[k][n])
    const int li = (b - 64) * 1024 + t;   // 0..49151
    const int l = li >> 14;
    const int i = li & 16383;
    const int n = i >> 7, k = i & 127;
    const float* W = (l == 0) ? W0 : ((l == 1) ? W1 : W2);
    Wt[li] = __half_as_ushort(__float2half_rn(W[k * D + n]));
  } else if (t < D) {       // ---- CA/CB fold bias+BN
    const int c = t;
    float A0 = g0[c] * rsqrtf(vr0[c] + 1e-5f);
    CA[c] = A0;
    CB[c] = (b0[c] - mu0[c]) * A0 + be0[c];
    float A1 = g1[c] * rsqrtf(vr1[c] + 1e-5f);
    CA[D + c] = A1;
    CB[D + c] = (b1[c] - mu1[c]) * A1 + be1[c];
    CA[2 * D + c] = 1.f;
    CB[2 * D + c] = b2[c];
  }
}

// ---- build2s: reduceN (totals/norms/in-place u8 prefix) + chunk sum; LAST block does
// ---- the serial exclusive scan of chunk sums (replaces the scan_serial dispatch).

__global__ __launch_bounds__(256) void k_build2s(uint* __restrict__ pd,
                                                 const uint* __restrict__ ps,
                                                 int* __restrict__ totd,
                                                 float* __restrict__ ns,
                                                 float* __restrict__ nd,
                                                 int* __restrict__ csum,
                                                 int* __restrict__ rofs,
                                                 int* __restrict__ ticket,
                                                 int N, int nch) {
  __shared__ int sd[256];
  __shared__ int lastf;
  const int t = threadIdx.x;
  const int j = blockIdx.x * 256 + t;    // packed uint index (4 nodes), j < PBU
  const int n0 = j * 4;
  uint r0 = 0, r1 = 0, r2 = 0, r3 = 0;
  uint s0 = 0, s1 = 0, s2 = 0, s3 = 0;
#pragma unroll
  for (int sl = 0; sl < NSL; ++sl) {
    const uint v = pd[(size_t)sl * PBU + j];
    pd[(size_t)sl * PBU + j] = r0 | (r1 << 8) | (r2 << 16) | (r3 << 24);
    r0 += v & 0xffu; r1 += (v >> 8) & 0xffu; r2 += (v >> 16) & 0xffu; r3 += (v >> 24) & 0xffu;
    const uint w = ps[(size_t)sl * PBU + j];
    s0 += w & 0xffu; s1 += (w >> 8) & 0xffu; s2 += (w >> 16) & 0xffu; s3 += (w >> 24) & 0xffu;
  }
  const uint rr[4] = {r0, r1, r2, r3};
  const uint ss[4] = {s0, s1, s2, s3};
  int tot = 0;
#pragma unroll
  for (int k = 0; k < 4; ++k) {
    if (n0 + k < N) {
      totd[n0 + k] = (int)rr[k];
      nd[n0 + k] = rsqrtf((float)max(rr[k], 1u));
      ns[n0 + k] = rsqrtf((float)max(ss[k], 1u));
      tot += (int)rr[k];
    }
  }
  sd[t] = tot; __syncthreads();
  for (int off = 128; off > 0; off >>= 1) {
    if (t < off) sd[t] += sd[t + off];
    __syncthreads();
  }
  if (t == 0) {
    csum[blockIdx.x] = sd[0];
    __threadfence();
    lastf = (atomicAdd(ticket, 1) == nch - 1) ? 1 : 0;
  }
  __syncthreads();
  if (lastf && t < 64) {
    __threadfence();
    int run = 0;
    for (int b0 = 0; b0 < nch; b0 += 64) {
      const int idx = b0 + t;
      int v = (idx < nch) ? __hip_atomic_load(&csum[idx], __ATOMIC_RELAXED,
                                              __HIP_MEMORY_SCOPE_AGENT) : 0;
      int sc = v;
#pragma unroll
      for (int off = 1; off < 64; off <<= 1) {
        int u = __shfl_up(sc, off);
        if (t >= off) sc += u;
      }
      if (idx < nch) csum[idx] = run + sc - v;
      run += __shfl(sc, 63);
    }
    if (t == 0) rofs[N] = run;
  }
}

// ---------------- final per-node rofs scan ----------------

__global__ __launch_bounds__(256) void k_scan_final(const int* __restrict__ totd,
                                                    const int* __restrict__ csum,
                                                    int* __restrict__ rofs, int n) {
  __shared__ int sd[256];
  const int b = blockIdx.x, t = threadIdx.x;
  const int base = b * 1024 + t * 4;
  int v[4]; int s = 0;
#pragma unroll
  for (int i = 0; i < 4; ++i) { v[i] = (base + i < n) ? totd[base + i] : 0; s += v[i]; }
  sd[t] = s; __syncthreads();
  for (int off = 1; off < 256; off <<= 1) {
    int x = (t >= off) ? sd[t - off] : 0;
    __syncthreads();
    sd[t] += x;
    __syncthreads();
  }
  int o = sd[t] - s + csum[b];
#pragma unroll
  for (int i = 0; i < 4; ++i) {
    if (base + i < n) { rofs[base + i] = o; o += v[i]; }
  }
}

// ---- sg: merged {layer-0 GEMM (f32 input, ns folded)} + {atomic-free scatter} ----
// blocks [0, GB): gemm32 tiles; blocks [GB, ...): scatter edges. Independent work.

__global__ __launch_bounds__(256) void k_sg(const float* __restrict__ X,
                                            const ushort* __restrict__ Wt,
                                            const float* __restrict__ ns,
                                            ushort* __restrict__ out,
                                            const int* __restrict__ esrc,
                                            const int* __restrict__ edst,
                                            const uchar* __restrict__ rank8,
                                            const uint* __restrict__ pd,
                                            const int* __restrict__ rofs,
                                            int* __restrict__ csr,
                                            int M, int E, uint Msb, int GB) {
  if ((int)blockIdx.x >= GB) {   // ---- scatter part
    const int i = ((int)blockIdx.x - GB) * 256 + threadIdx.x;
    if (i < E) {
      const int d = edst[i];
      const uint sl = mdiv40((uint)i, Msb);
      const uint pk = pd[(size_t)sl * PBU + (d >> 2)];
      const uint pfx = (pk >> ((uint)(d & 3) * 8u)) & 0xffu;
      csr[rofs[d] + (int)pfx + (int)rank8[i]] = esrc[i];
    }
    return;
  }
  // ---- gemm32 part
  const int lane = threadIdx.x & 63;
  const int wv = threadIdx.x >> 6;
  const int m0 = (blockIdx.x * 4 + wv) * 32;
  if (m0 >= M) return;
  const int lr = lane & 15;
  const int kg = (lane >> 4) * 8;

  half8 hf[2][4];
  const half8 hz = {};
#pragma unroll
  for (int mt = 0; mt < 2; ++mt) {
    const int row = m0 + mt * 16 + lr;
    if (row < M) {
      const float s = ns[row];
#pragma unroll
      for (int kt = 0; kt < 4; ++kt) {
        const float4 a = *reinterpret_cast<const float4*>(X + (size_t)row * D + kt * 32 + kg);
        const float4 b = *reinterpret_cast<const float4*>(X + (size_t)row * D + kt * 32 + kg + 4);
        half8 hv;
        hv[0] = (_Float16)(a.x * s); hv[1] = (_Float16)(a.y * s);
        hv[2] = (_Float16)(a.z * s); hv[3] = (_Float16)(a.w * s);
        hv[4] = (_Float16)(b.x * s); hv[5] = (_Float16)(b.y * s);
        hv[6] = (_Float16)(b.z * s); hv[7] = (_Float16)(b.w * s);
        hf[mt][kt] = hv;
      }
    } else {
#pragma unroll
      for (int kt = 0; kt < 4; ++kt) hf[mt][kt] = hz;
    }
  }

  f32x4 acc[8][2];
#pragma unroll
  for (int nt = 0; nt < 8; ++nt) { acc[nt][0] = (f32x4)(0.f); acc[nt][1] = (f32x4)(0.f); }

#pragma unroll
  for (int nt = 0; nt < 8; ++nt) {
    const ushort* wb = Wt + (size_t)(nt * 16 + lr) * D + kg;
#pragma unroll
    for (int kt = 0; kt < 4; ++kt) {
      half8 wf = *reinterpret_cast<const half8*>(wb + kt * 32);
      acc[nt][0] = __builtin_amdgcn_mfma_f32_16x16x32_f16(wf, hf[0][kt], acc[nt][0], 0, 0, 0);
      acc[nt][1] = __builtin_amdgcn_mfma_f32_16x16x32_f16(wf, hf[1][kt], acc[nt][1], 0, 0, 0);
    }
  }

  const int mo = lane & 15;
  const int no = (lane >> 4) * 4;
#pragma unroll
  for (int mt = 0; mt < 2; ++mt) {
    const int row = m0 + mt * 16 + mo;
    if (row < M) {
#pragma unroll
      for (int nt = 0; nt < 8; ++nt) {
        uint2 u;
        u.x = pack_f16x2(acc[nt][mt][0], acc[nt][mt][1]);
        u.y = pack_f16x2(acc[nt][mt][2], acc[nt][mt][3]);
        *reinterpret_cast<uint2*>(out + (size_t)row * D + nt * 16 + no) = u;
      }
    }
  }
}

// ---------------- MFMA GEMM (f16 in, f16 out) ----------------

__global__ __launch_bounds__(256) void k_gemm16(const ushort* __restrict__ A,
                                                const ushort* __restrict__ Wt,
                                                ushort* __restrict__ out, int M) {
  const int lane = threadIdx.x & 63;
  const int wv = threadIdx.x >> 6;
  const int m0 = (blockIdx.x * 4 + wv) * 32;
  if (m0 >= M) return;
  const int lr = lane & 15;
  const int kg = (lane >> 4) * 8;

  half8 hf[2][4];
  const half8 hz = {};
#pragma unroll
  for (int mt = 0; mt < 2; ++mt) {
    const int row = m0 + mt * 16 + lr;
    const bool ok = row < M;
#pragma unroll
    for (int kt = 0; kt < 4; ++kt)
      hf[mt][kt] = ok ? *reinterpret_cast<const half8*>(A + (size_t)row * D + kt * 32 + kg)
                      : hz;
  }

  f32x4 acc[8][2];
#pragma unroll
  for (int nt = 0; nt < 8; ++nt) { acc[nt][0] = (f32x4)(0.f); acc[nt][1] = (f32x4)(0.f); }

#pragma unroll
  for (int nt = 0; nt < 8; ++nt) {
    const ushort* wb = Wt + (size_t)(nt * 16 + lr) * D + kg;
#pragma unroll
    for (int kt = 0; kt < 4; ++kt) {
      half8 wf = *reinterpret_cast<const half8*>(wb + kt * 32);
      acc[nt][0] = __builtin_amdgcn_mfma_f32_16x16x32_f16(wf, hf[0][kt], acc[nt][0], 0, 0, 0);
      acc[nt][1] = __builtin_amdgcn_mfma_f32_16x16x32_f16(wf, hf[1][kt], acc[nt][1], 0, 0, 0);
    }
  }

  const int mo = lane & 15;
  const int no = (lane >> 4) * 4;
#pragma unroll
  for (int mt = 0; mt < 2; ++mt) {
    const int row = m0 + mt * 16 + mo;
    if (row < M) {
#pragma unroll
      for (int nt = 0; nt < 8; ++nt) {
        uint2 u;
        u.x = pack_f16x2(acc[nt][mt][0], acc[nt][mt][1]);
        u.y = pack_f16x2(acc[nt][mt][2], acc[nt][mt][3]);
        *reinterpret_cast<uint2*>(out + (size_t)row * D + nt * 16 + no) = u;
      }
    }
  }
}

// ---------------- SpMM: 16-lane group per dst row (4 rows/wave), 4-deep clamped gather ----

__global__ __launch_bounds__(256) void k_spmm16(const uint* __restrict__ hs,
                                                const int* __restrict__ csr,
                                                const int* __restrict__ rofs,
                                                const float* __restrict__ nd,
                                                const float* __restrict__ ns,
                                                const float* __restrict__ CA,
                                                const float* __restrict__ CB,
                                                float* __restrict__ outf,
                                                uint* __restrict__ hnext,
                                                int N, int last) {
  const int t = threadIdx.x;
  const int lane = t & 63;
  const int c16 = lane & 15;       // col group: this lane owns cols c16*8..c16*8+7
  const int gb = lane & ~15;       // group's base lane within the wave
  const int d = blockIdx.x * 16 + (t >> 4);
  if (d >= N) return;              // uniform per 16-lane group; shfl stays intra-group
  const int beg = rofs[d], end = rofs[d + 1];

  float acc[8];
#pragma unroll
  for (int j = 0; j < 8; ++j) acc[j] = 0.f;

  for (int base = beg; base < end; base += 16) {
    const int len = min(16, end - base);
    // 16-lane coalesced index load (clamped -> always defined for shfl)
    const int idx = csr[min(base + c16, end - 1)];
#pragma unroll 1
    for (int j = 0; j < len; j += 4) {
      // clamped source slots: tail gathers duplicate the last edge (L1 hit),
      // accumulation weighted 0 so the sum is exact; control flow stays flat.
      const int l1 = min(j + 1, len - 1), l2 = min(j + 2, len - 1), l3 = min(j + 3, len - 1);
      const int s0 = __shfl(idx, gb + j);
      const int s1 = __shfl(idx, gb + l1);
      const int s2 = __shfl(idx, gb + l2);
      const int s3 = __shfl(idx, gb + l3);
      const float w1 = (j + 1 < len) ? 1.f : 0.f;
      const float w2 = (j + 2 < len) ? 1.f : 0.f;
      const float w3 = (j + 3 < len) ? 1.f : 0.f;
      const uint4 v0 = *reinterpret_cast<const uint4*>(hs + (size_t)s0 * 64 + c16 * 4);
      const uint4 v1 = *reinterpret_cast<const uint4*>(hs + (size_t)s1 * 64 + c16 * 4);
      const uint4 v2 = *reinterpret_cast<const uint4*>(hs + (size_t)s2 * 64 + c16 * 4);
      const uint4 v3 = *reinterpret_cast<const uint4*>(hs + (size_t)s3 * 64 + c16 * 4);
#pragma unroll
      for (int q = 0; q < 4; ++q) {
        const uint u0 = (&v0.x)[q], u1 = (&v1.x)[q], u2 = (&v2.x)[q], u3 = (&v3.x)[q];
        const float2 a0 = unpack_f16x2(u0);
        const float2 a1 = unpack_f16x2(u1);
        const float2 a2 = unpack_f16x2(u2);
        const float2 a3 = unpack_f16x2(u3);
        acc[q * 2]     += a0.x;
        acc[q * 2 + 1] += a0.y;
        acc[q * 2]     = fmaf(a1.x, w1, acc[q * 2]);
        acc[q * 2 + 1] = fmaf(a1.y, w1, acc[q * 2 + 1]);
        acc[q * 2]     = fmaf(a2.x, w2, acc[q * 2]);
        acc[q * 2 + 1] = fmaf(a2.y, w2, acc[q * 2 + 1]);
        acc[q * 2]     = fmaf(a3.x, w3, acc[q * 2]);
        acc[q * 2 + 1] = fmaf(a3.y, w3, acc[q * 2 + 1]);
      }
    }
  }

  const float ndv = nd[d];
  const float4 ca0 = *reinterpret_cast<const float4*>(CA + c16 * 8);
  const float4 ca1 = *reinterpret_cast<const float4*>(CA + c16 * 8 + 4);
  const float4 cb0 = *reinterpret_cast<const float4*>(CB + c16 * 8);
  const float4 cb1 = *reinterpret_cast<const float4*>(CB + c16 * 8 + 4);
  float r[8];
  r[0] = acc[0] * ndv * ca0.x + cb0.x;
  r[1] = acc[1] * ndv * ca0.y + cb0.y;
  r[2] = acc[2] * ndv * ca0.z + cb0.z;
  r[3] = acc[3] * ndv * ca0.w + cb0.w;
  r[4] = acc[4] * ndv * ca1.x + cb1.x;
  r[5] = acc[5] * ndv * ca1.y + cb1.y;
  r[6] = acc[6] * ndv * ca1.z + cb1.z;
  r[7] = acc[7] * ndv * ca1.w + cb1.w;
  if (!last) {
    const float s = ns[d];
#pragma unroll
    for (int j = 0; j < 8; ++j) r[j] = fmaxf(r[j], 0.f) * s;
    uint4 u;
    u.x = pack_f16x2(r[0], r[1]);
    u.y = pack_f16x2(r[2], r[3]);
    u.z = pack_f16x2(r[4], r[5]);
    u.w = pack_f16x2(r[6], r[7]);
    *reinterpret_cast<uint4*>(hnext + (size_t)d * 64 + c16 * 4) = u;
  } else {
    float4 o0 = make_float4(r[0], r[1], r[2], r[3]);
    float4 o1 = make_float4(r[4], r[5], r[6], r[7]);
    *reinterpret_cast<float4*>(outf + (size_t)d * D + c16 * 8) = o0;
    *reinterpret_cast<float4*>(outf + (size_t)d * D + c16 * 8 + 4) = o1;
  }
}

// ---------------- launch ----------------

extern "C" void kernel_launch(void* const* d_in, const int* in_sizes, int n_in,
                              void* d_out, int out_size, void* d_ws, size_t ws_size,
                              hipStream_t stream) {
  const float* x = (const float*)d_in[0];
  const int* esrc = (const int*)d_in[1];
  const int* edst = (const int*)d_in[2];
  const float* W0 = (const float*)d_in[3];
  const float* b0 = (const float*)d_in[4];
  const float* W1 = (const float*)d_in[5];
  const float* b1 = (const float*)d_in[6];
  const float* W2 = (const float*)d_in[7];
  const float* b2 = (const float*)d_in[8];
  const float* g0 = (const float*)d_in[9];
  const float* be0 = (const float*)d_in[10];
  const float* m0 = (const float*)d_in[11];
  const float* v0 = (const float*)d_in[12];
  const float* g1 = (const float*)d_in[13];
  const float* be1 = (const float*)d_in[14];
  const float* m1 = (const float*)d_in[15];
  const float* v1 = (const float*)d_in[16];
  const int N = in_sizes[0] / D;
  const int E = in_sizes[1];

  const int SB = (E + NSL - 1) / NSL;
  const uint Msb = (uint)(((1ULL << 40) + (unsigned long long)SB - 1) / (unsigned long long)SB);

  char* p = (char*)d_ws;
  auto carve = [&](size_t bytes) {
    char* r = p;
    p += (bytes + 255) & ~(size_t)255;
    return (void*)r;
  };
  uint* hs16 = (uint*)carve((size_t)N * 64 * 4);           // GEMM out / SpMM in (f16 packed)
  ushort* Wt = (ushort*)carve((size_t)3 * D * D * 2);
  float* CA = (float*)carve((size_t)3 * D * 4);
  float* CB = (float*)carve((size_t)3 * D * 4);
  float* ns = (float*)carve((size_t)N * 4);
  float* nd = (float*)carve((size_t)N * 4);
  uint* pd = (uint*)carve((size_t)NSL * PBU * 4);
  uint* ps = (uint*)carve((size_t)NSL * PBU * 4);
  uchar* rank8 = (uchar*)carve((size_t)E);
  int* totd = (int*)carve((size_t)N * 4);
  int* rofs = (int*)carve((size_t)(N + 1) * 4);
  const int nch = (N + 1023) / 1024;
  int* csum = (int*)carve((size_t)nch * 4);
  int* ticket = (int*)carve(256);
  int* csr = (int*)carve((size_t)E * 4);
  uint* bufA = (uint*)d_out;  // inter-layer f16 ping buffer lives in d_out (fully rewritten)

  hipMemsetAsync(ticket, 0, 4, stream);
  k_build1<<<113, 1024, 0, stream>>>(esrc, edst, W0, W1, W2, b0, b1, b2,
                                     g0, be0, m0, v0, g1, be1, m1, v1,
                                     pd, ps, rank8, Wt, CA, CB, E, SB);
  k_build2s<<<nch, 256, 0, stream>>>(pd, ps, totd, ns, nd, csum, rofs, ticket, N, nch);
  k_scan_final<<<nch, 256, 0, stream>>>(totd, csum, rofs, N);

  const int gb = (N + 127) / 128;
  const int sb = (N + 15) / 16;
  const int scb = (E + 255) / 256;
  // layer 0 GEMM (f32 input) + scatter, merged (independent work)
  k_sg<<<gb + scb, 256, 0, stream>>>(x, Wt, ns, (ushort*)hs16, esrc, edst, rank8, pd, rofs,
                                     csr, N, E, Msb, gb);
  k_spmm16<<<sb, 256, 0, stream>>>(hs16, csr, rofs, nd, ns, CA, CB, nullptr, bufA, N, 0);
  // layer 1
  k_gemm16<<<gb, 256, 0, stream>>>((const ushort*)bufA, Wt + 16384, (ushort*)hs16, N);
  k_spmm16<<<sb, 256, 0, stream>>>(hs16, csr, rofs, nd, ns, CA + D, CB + D, nullptr, bufA, N, 0);
  // layer 2
  k_gemm16<<<gb, 256, 0, stream>>>((const ushort*)bufA, Wt + 32768, (ushort*)hs16, N);
  k_spmm16<<<sb, 256, 0, stream>>>(hs16, csr, rofs, nd, ns, CA + 2 * D, CB + 2 * D,
                                   (float*)d_out, nullptr, N, 1);
}

// Round 13
// 226.377 us; speedup vs baseline: 2.3805x; 1.1120x over previous
//
#include <hip/hip_runtime.h>
#include <hip/hip_fp16.h>
#include <math.h>

#define D 128
#define NSL 32          // edge slices
#define PBU 25088       // packed u8 counters (uints) -> supports N <= 100352

typedef _Float16 half8 __attribute__((ext_vector_type(8)));
typedef float f32x4 __attribute__((ext_vector_type(4)));

__device__ inline uint pack_f16x2(float a, float b) {
  __half2 h = __floats2half2_rn(a, b);
  return *reinterpret_cast<uint*>(&h);
}
__device__ inline float2 unpack_f16x2(uint p) {
  __half2 h = *reinterpret_cast<__half2*>(&p);
  return __half22float2(h);
}
__device__ inline uint mdiv40(uint x, uint M) {  // x / d with M = ceil(2^40/d)
  return (uint)(((unsigned long long)x * M) >> 40);
}

// ---------------- build1: fused {dst-hist+rank, src-hist, Wt transpose, CA/CB} ----------

__global__ __launch_bounds__(1024) void k_build1(const int* __restrict__ esrc,
                                                 const int* __restrict__ edst,
                                                 const float* __restrict__ W0,
                                                 const float* __restrict__ W1,
                                                 const float* __restrict__ W2,
                                                 const float* __restrict__ b0,
                                                 const float* __restrict__ b1,
                                                 const float* __restrict__ b2,
                                                 const float* __restrict__ g0,
                                                 const float* __restrict__ be0,
                                                 const float* __restrict__ mu0,
                                                 const float* __restrict__ vr0,
                                                 const float* __restrict__ g1,
                                                 const float* __restrict__ be1,
                                                 const float* __restrict__ mu1,
                                                 const float* __restrict__ vr1,
                                                 uint* __restrict__ pd,
                                                 uint* __restrict__ ps,
                                                 uchar* __restrict__ rank8,
                                                 ushort* __restrict__ Wt,
                                                 float* __restrict__ CA,
                                                 float* __restrict__ CB,
                                                 int E, int SB) {
  __shared__ uint h[PBU];   // ~98 KB static LDS (hist blocks only)
  const int b = blockIdx.x;
  const int t = threadIdx.x;
  if (b < 32) {             // ---- dst histogram + rank record
    for (int j = t; j < PBU; j += 1024) h[j] = 0u;
    __syncthreads();
    const int i0 = b * SB, i1 = min(i0 + SB, E);
    for (int i = i0 + t; i < i1; i += 1024) {
      const int d = edst[i];
      const uint sh = (uint)(d & 3) * 8u;
      const uint old = atomicAdd(&h[d >> 2], 1u << sh);
      rank8[i] = (uchar)((old >> sh) & 0xffu);
    }
    __syncthreads();
    uint* p = pd + (size_t)b * PBU;
    for (int j = t; j < PBU; j += 1024) p[j] = h[j];
  } else if (b < 64) {      // ---- src histogram (counts only)
    const int sl = b - 32;
    for (int j = t; j < PBU; j += 1024) h[j] = 0u;
    __syncthreads();
    const int i0 = sl * SB, i1 = min(i0 + SB, E);
    for (int i = i0 + t; i < i1; i += 1024) {
      const int s = esrc[i];
      atomicAdd(&h[s >> 2], 1u << ((uint)(s & 3) * 8u));
    }
    __syncthreads();
    uint* p = ps + (size_t)sl * PBU;
    for (int j = t; j < PBU; j += 1024) p[j] = h[j];
  } else if (b < 112) {     // ---- Wt[l][n][k] = f16(W_l[k][n])
    const int li = (b - 64) * 1024 + t;   // 0..49151
    const int l = li >> 14;
    const int i = li & 16383;
    const int n = i >> 7, k = i & 127;
    const float* W = (l == 0) ? W0 : ((l == 1) ? W1 : W2);
    Wt[li] = __half_as_ushort(__float2half_rn(W[k * D + n]));
  } else if (t < D) {       // ---- CA/CB fold bias+BN
    const int c = t;
    float A0 = g0[c] * rsqrtf(vr0[c] + 1e-5f);
    CA[c] = A0;
    CB[c] = (b0[c] - mu0[c]) * A0 + be0[c];
    float A1 = g1[c] * rsqrtf(vr1[c] + 1e-5f);
    CA[D + c] = A1;
    CB[D + c] = (b1[c] - mu1[c]) * A1 + be1[c];
    CA[2 * D + c] = 1.f;
    CB[2 * D + c] = b2[c];
  }
}

// ---- build2s: reduceN + chunk sum; LAST block serial-scans chunk sums ----

__global__ __launch_bounds__(256) void k_build2s(uint* __restrict__ pd,
                                                 const uint* __restrict__ ps,
                                                 int* __restrict__ totd,
                                                 float* __restrict__ ns,
                                                 float* __restrict__ nd,
                                                 int* __restrict__ csum,
                                                 int* __restrict__ rofs,
                                                 int* __restrict__ ticket,
                                                 int N, int nch) {
  __shared__ int sd[256];
  __shared__ int lastf;
  const int t = threadIdx.x;
  const int j = blockIdx.x * 256 + t;    // packed uint index (4 nodes), j < PBU
  const int n0 = j * 4;
  uint r0 = 0, r1 = 0, r2 = 0, r3 = 0;
  uint s0 = 0, s1 = 0, s2 = 0, s3 = 0;
#pragma unroll
  for (int sl = 0; sl < NSL; ++sl) {
    const uint v = pd[(size_t)sl * PBU + j];
    pd[(size_t)sl * PBU + j] = r0 | (r1 << 8) | (r2 << 16) | (r3 << 24);
    r0 += v & 0xffu; r1 += (v >> 8) & 0xffu; r2 += (v >> 16) & 0xffu; r3 += (v >> 24) & 0xffu;
    const uint w = ps[(size_t)sl * PBU + j];
    s0 += w & 0xffu; s1 += (w >> 8) & 0xffu; s2 += (w >> 16) & 0xffu; s3 += (w >> 24) & 0xffu;
  }
  const uint rr[4] = {r0, r1, r2, r3};
  const uint ss[4] = {s0, s1, s2, s3};
  int tot = 0;
#pragma unroll
  for (int k = 0; k < 4; ++k) {
    if (n0 + k < N) {
      totd[n0 + k] = (int)rr[k];
      nd[n0 + k] = rsqrtf((float)max(rr[k], 1u));
      ns[n0 + k] = rsqrtf((float)max(ss[k], 1u));
      tot += (int)rr[k];
    }
  }
  sd[t] = tot; __syncthreads();
  for (int off = 128; off > 0; off >>= 1) {
    if (t < off) sd[t] += sd[t + off];
    __syncthreads();
  }
  if (t == 0) {
    csum[blockIdx.x] = sd[0];
    __threadfence();
    lastf = (atomicAdd(ticket, 1) == nch - 1) ? 1 : 0;
  }
  __syncthreads();
  if (lastf && t < 64) {
    __threadfence();
    int run = 0;
    for (int b0 = 0; b0 < nch; b0 += 64) {
      const int idx = b0 + t;
      int v = (idx < nch) ? __hip_atomic_load(&csum[idx], __ATOMIC_RELAXED,
                                              __HIP_MEMORY_SCOPE_AGENT) : 0;
      int sc = v;
#pragma unroll
      for (int off = 1; off < 64; off <<= 1) {
        int u = __shfl_up(sc, off);
        if (t >= off) sc += u;
      }
      if (idx < nch) csum[idx] = run + sc - v;
      run += __shfl(sc, 63);
    }
    if (t == 0) rofs[N] = run;
  }
}

// ---------------- final per-node rofs scan ----------------

__global__ __launch_bounds__(256) void k_scan_final(const int* __restrict__ totd,
                                                    const int* __restrict__ csum,
                                                    int* __restrict__ rofs, int n) {
  __shared__ int sd[256];
  const int b = blockIdx.x, t = threadIdx.x;
  const int base = b * 1024 + t * 4;
  int v[4]; int s = 0;
#pragma unroll
  for (int i = 0; i < 4; ++i) { v[i] = (base + i < n) ? totd[base + i] : 0; s += v[i]; }
  sd[t] = s; __syncthreads();
  for (int off = 1; off < 256; off <<= 1) {
    int x = (t >= off) ? sd[t - off] : 0;
    __syncthreads();
    sd[t] += x;
    __syncthreads();
  }
  int o = sd[t] - s + csum[b];
#pragma unroll
  for (int i = 0; i < 4; ++i) {
    if (base + i < n) { rofs[base + i] = o; o += v[i]; }
  }
}

// ---- sg: merged {layer-0 GEMM (f32 input, ns folded)} + {atomic-free scatter} ----

__global__ __launch_bounds__(256) void k_sg(const float* __restrict__ X,
                                            const ushort* __restrict__ Wt,
                                            const float* __restrict__ ns,
                                            ushort* __restrict__ out,
                                            const int* __restrict__ esrc,
                                            const int* __restrict__ edst,
                                            const uchar* __restrict__ rank8,
                                            const uint* __restrict__ pd,
                                            const int* __restrict__ rofs,
                                            int* __restrict__ csr,
                                            int M, int E, uint Msb, int GB) {
  if ((int)blockIdx.x >= GB) {   // ---- scatter part
    const int i = ((int)blockIdx.x - GB) * 256 + threadIdx.x;
    if (i < E) {
      const int d = edst[i];
      const uint sl = mdiv40((uint)i, Msb);
      const uint pk = pd[(size_t)sl * PBU + (d >> 2)];
      const uint pfx = (pk >> ((uint)(d & 3) * 8u)) & 0xffu;
      csr[rofs[d] + (int)pfx + (int)rank8[i]] = esrc[i];
    }
    return;
  }
  // ---- gemm32 part
  const int lane = threadIdx.x & 63;
  const int wv = threadIdx.x >> 6;
  const int m0 = (blockIdx.x * 4 + wv) * 32;
  if (m0 >= M) return;
  const int lr = lane & 15;
  const int kg = (lane >> 4) * 8;

  half8 hf[2][4];
  const half8 hz = {};
#pragma unroll
  for (int mt = 0; mt < 2; ++mt) {
    const int row = m0 + mt * 16 + lr;
    if (row < M) {
      const float s = ns[row];
#pragma unroll
      for (int kt = 0; kt < 4; ++kt) {
        const float4 a = *reinterpret_cast<const float4*>(X + (size_t)row * D + kt * 32 + kg);
        const float4 b = *reinterpret_cast<const float4*>(X + (size_t)row * D + kt * 32 + kg + 4);
        half8 hv;
        hv[0] = (_Float16)(a.x * s); hv[1] = (_Float16)(a.y * s);
        hv[2] = (_Float16)(a.z * s); hv[3] = (_Float16)(a.w * s);
        hv[4] = (_Float16)(b.x * s); hv[5] = (_Float16)(b.y * s);
        hv[6] = (_Float16)(b.z * s); hv[7] = (_Float16)(b.w * s);
        hf[mt][kt] = hv;
      }
    } else {
#pragma unroll
      for (int kt = 0; kt < 4; ++kt) hf[mt][kt] = hz;
    }
  }

  f32x4 acc[8][2];
#pragma unroll
  for (int nt = 0; nt < 8; ++nt) { acc[nt][0] = (f32x4)(0.f); acc[nt][1] = (f32x4)(0.f); }

#pragma unroll
  for (int nt = 0; nt < 8; ++nt) {
    const ushort* wb = Wt + (size_t)(nt * 16 + lr) * D + kg;
#pragma unroll
    for (int kt = 0; kt < 4; ++kt) {
      half8 wf = *reinterpret_cast<const half8*>(wb + kt * 32);
      acc[nt][0] = __builtin_amdgcn_mfma_f32_16x16x32_f16(wf, hf[0][kt], acc[nt][0], 0, 0, 0);
      acc[nt][1] = __builtin_amdgcn_mfma_f32_16x16x32_f16(wf, hf[1][kt], acc[nt][1], 0, 0, 0);
    }
  }

  const int mo = lane & 15;
  const int no = (lane >> 4) * 4;
#pragma unroll
  for (int mt = 0; mt < 2; ++mt) {
    const int row = m0 + mt * 16 + mo;
    if (row < M) {
#pragma unroll
      for (int nt = 0; nt < 8; ++nt) {
        uint2 u;
        u.x = pack_f16x2(acc[nt][mt][0], acc[nt][mt][1]);
        u.y = pack_f16x2(acc[nt][mt][2], acc[nt][mt][3]);
        *reinterpret_cast<uint2*>(out + (size_t)row * D + nt * 16 + no) = u;
      }
    }
  }
}

// ---- k_spgm: FUSED spmm + next-layer GEMM. Block owns 128 dst rows.
// Phase A: 16-lane group g computes rows g+16r (r=0..7): gather+norm+bias+BN+relu+*ns -> f16
//          into LDS A[128][136] (consecutive groups -> consecutive rows: 2-way banks only).
// Phase B: each of 4 waves MFMAs its 32-row tile from LDS vs Wt (L2-hot) -> hs16 out.

__global__ __launch_bounds__(256) void k_spgm(const uint* __restrict__ hs,
                                              const int* __restrict__ csr,
                                              const int* __restrict__ rofs,
                                              const float* __restrict__ nd,
                                              const float* __restrict__ ns,
                                              const float* __restrict__ CA,
                                              const float* __restrict__ CB,
                                              const ushort* __restrict__ Wt,
                                              ushort* __restrict__ out, int N) {
  __shared__ ushort A[128 * 136];   // 34816 B; row stride 272 B (16B-aligned)
  const int t = threadIdx.x;
  const int lane = t & 63;
  const int c16 = lane & 15;
  const int gb = lane & ~15;
  const int g = t >> 4;            // group 0..15
  const int rbase = blockIdx.x * 128;

  // ---- Phase A: spmm into LDS ----
#pragma unroll 1
  for (int r = 0; r < 8; ++r) {
    const int rl = g + 16 * r;     // row_local 0..127
    const int d = rbase + rl;
    uint4 uo = make_uint4(0u, 0u, 0u, 0u);
    if (d < N) {
      const int beg = rofs[d], end = rofs[d + 1];
      float acc[8];
#pragma unroll
      for (int j = 0; j < 8; ++j) acc[j] = 0.f;
      for (int eb = beg; eb < end; eb += 16) {
        const int len = min(16, end - eb);
        const int idx = csr[min(eb + c16, end - 1)];
#pragma unroll 1
        for (int j = 0; j < len; j += 4) {
          const int l1 = min(j + 1, len - 1), l2 = min(j + 2, len - 1), l3 = min(j + 3, len - 1);
          const int s0 = __shfl(idx, gb + j);
          const int s1 = __shfl(idx, gb + l1);
          const int s2 = __shfl(idx, gb + l2);
          const int s3 = __shfl(idx, gb + l3);
          const float w1 = (j + 1 < len) ? 1.f : 0.f;
          const float w2 = (j + 2 < len) ? 1.f : 0.f;
          const float w3 = (j + 3 < len) ? 1.f : 0.f;
          const uint4 v0 = *reinterpret_cast<const uint4*>(hs + (size_t)s0 * 64 + c16 * 4);
          const uint4 v1 = *reinterpret_cast<const uint4*>(hs + (size_t)s1 * 64 + c16 * 4);
          const uint4 v2 = *reinterpret_cast<const uint4*>(hs + (size_t)s2 * 64 + c16 * 4);
          const uint4 v3 = *reinterpret_cast<const uint4*>(hs + (size_t)s3 * 64 + c16 * 4);
#pragma unroll
          for (int q = 0; q < 4; ++q) {
            const float2 a0 = unpack_f16x2((&v0.x)[q]);
            const float2 a1 = unpack_f16x2((&v1.x)[q]);
            const float2 a2 = unpack_f16x2((&v2.x)[q]);
            const float2 a3 = unpack_f16x2((&v3.x)[q]);
            acc[q * 2]     += a0.x;
            acc[q * 2 + 1] += a0.y;
            acc[q * 2]     = fmaf(a1.x, w1, acc[q * 2]);
            acc[q * 2 + 1] = fmaf(a1.y, w1, acc[q * 2 + 1]);
            acc[q * 2]     = fmaf(a2.x, w2, acc[q * 2]);
            acc[q * 2 + 1] = fmaf(a2.y, w2, acc[q * 2 + 1]);
            acc[q * 2]     = fmaf(a3.x, w3, acc[q * 2]);
            acc[q * 2 + 1] = fmaf(a3.y, w3, acc[q * 2 + 1]);
          }
        }
      }
      const float ndv = nd[d];
      const float s = ns[d];
      const float4 ca0 = *reinterpret_cast<const float4*>(CA + c16 * 8);
      const float4 ca1 = *reinterpret_cast<const float4*>(CA + c16 * 8 + 4);
      const float4 cb0 = *reinterpret_cast<const float4*>(CB + c16 * 8);
      const float4 cb1 = *reinterpret_cast<const float4*>(CB + c16 * 8 + 4);
      float rv[8];
      rv[0] = acc[0] * ndv * ca0.x + cb0.x;
      rv[1] = acc[1] * ndv * ca0.y + cb0.y;
      rv[2] = acc[2] * ndv * ca0.z + cb0.z;
      rv[3] = acc[3] * ndv * ca0.w + cb0.w;
      rv[4] = acc[4] * ndv * ca1.x + cb1.x;
      rv[5] = acc[5] * ndv * ca1.y + cb1.y;
      rv[6] = acc[6] * ndv * ca1.z + cb1.z;
      rv[7] = acc[7] * ndv * ca1.w + cb1.w;
#pragma unroll
      for (int j = 0; j < 8; ++j) rv[j] = fmaxf(rv[j], 0.f) * s;
      uo.x = pack_f16x2(rv[0], rv[1]);
      uo.y = pack_f16x2(rv[2], rv[3]);
      uo.z = pack_f16x2(rv[4], rv[5]);
      uo.w = pack_f16x2(rv[6], rv[7]);
    }
    *reinterpret_cast<uint4*>(&A[rl * 136 + c16 * 8]) = uo;
  }
  __syncthreads();

  // ---- Phase B: GEMM from LDS ----
  const int w = t >> 6;
  const int m0l = w * 32;
  const int m0 = rbase + m0l;
  if (m0 >= N) return;
  const int lr = lane & 15;
  const int kg = (lane >> 4) * 8;
  half8 hf[2][4];
#pragma unroll
  for (int mt = 0; mt < 2; ++mt) {
    const int row_l = m0l + mt * 16 + lr;
#pragma unroll
    for (int kt = 0; kt < 4; ++kt)
      hf[mt][kt] = *reinterpret_cast<const half8*>(&A[row_l * 136 + kt * 32 + kg]);
  }
  const int no = (lane >> 4) * 4;
#pragma unroll
  for (int nt = 0; nt < 8; ++nt) {
    f32x4 a0 = (f32x4)(0.f), a1 = (f32x4)(0.f);
    const ushort* wb = Wt + (size_t)(nt * 16 + lr) * D + kg;
#pragma unroll
    for (int kt = 0; kt < 4; ++kt) {
      half8 wf = *reinterpret_cast<const half8*>(wb + kt * 32);
      a0 = __builtin_amdgcn_mfma_f32_16x16x32_f16(wf, hf[0][kt], a0, 0, 0, 0);
      a1 = __builtin_amdgcn_mfma_f32_16x16x32_f16(wf, hf[1][kt], a1, 0, 0, 0);
    }
    const int r0 = m0 + lr, r1 = m0 + 16 + lr;
    if (r0 < N) {
      uint2 u; u.x = pack_f16x2(a0[0], a0[1]); u.y = pack_f16x2(a0[2], a0[3]);
      *reinterpret_cast<uint2*>(out + (size_t)r0 * D + nt * 16 + no) = u;
    }
    if (r1 < N) {
      uint2 u; u.x = pack_f16x2(a1[0], a1[1]); u.y = pack_f16x2(a1[2], a1[3]);
      *reinterpret_cast<uint2*>(out + (size_t)r1 * D + nt * 16 + no) = u;
    }
  }
}

// ---------------- SpMM (standalone, final layer -> fp32 out) ----------------

__global__ __launch_bounds__(256) void k_spmm16(const uint* __restrict__ hs,
                                                const int* __restrict__ csr,
                                                const int* __restrict__ rofs,
                                                const float* __restrict__ nd,
                                                const float* __restrict__ CA,
                                                const float* __restrict__ CB,
                                                float* __restrict__ outf, int N) {
  const int t = threadIdx.x;
  const int lane = t & 63;
  const int c16 = lane & 15;
  const int gb = lane & ~15;
  const int d = blockIdx.x * 16 + (t >> 4);
  if (d >= N) return;
  const int beg = rofs[d], end = rofs[d + 1];

  float acc[8];
#pragma unroll
  for (int j = 0; j < 8; ++j) acc[j] = 0.f;

  for (int base = beg; base < end; base += 16) {
    const int len = min(16, end - base);
    const int idx = csr[min(base + c16, end - 1)];
#pragma unroll 1
    for (int j = 0; j < len; j += 4) {
      const int l1 = min(j + 1, len - 1), l2 = min(j + 2, len - 1), l3 = min(j + 3, len - 1);
      const int s0 = __shfl(idx, gb + j);
      const int s1 = __shfl(idx, gb + l1);
      const int s2 = __shfl(idx, gb + l2);
      const int s3 = __shfl(idx, gb + l3);
      const float w1 = (j + 1 < len) ? 1.f : 0.f;
      const float w2 = (j + 2 < len) ? 1.f : 0.f;
      const float w3 = (j + 3 < len) ? 1.f : 0.f;
      const uint4 v0 = *reinterpret_cast<const uint4*>(hs + (size_t)s0 * 64 + c16 * 4);
      const uint4 v1 = *reinterpret_cast<const uint4*>(hs + (size_t)s1 * 64 + c16 * 4);
      const uint4 v2 = *reinterpret_cast<const uint4*>(hs + (size_t)s2 * 64 + c16 * 4);
      const uint4 v3 = *reinterpret_cast<const uint4*>(hs + (size_t)s3 * 64 + c16 * 4);
#pragma unroll
      for (int q = 0; q < 4; ++q) {
        const float2 a0 = unpack_f16x2((&v0.x)[q]);
        const float2 a1 = unpack_f16x2((&v1.x)[q]);
        const float2 a2 = unpack_f16x2((&v2.x)[q]);
        const float2 a3 = unpack_f16x2((&v3.x)[q]);
        acc[q * 2]     += a0.x;
        acc[q * 2 + 1] += a0.y;
        acc[q * 2]     = fmaf(a1.x, w1, acc[q * 2]);
        acc[q * 2 + 1] = fmaf(a1.y, w1, acc[q * 2 + 1]);
        acc[q * 2]     = fmaf(a2.x, w2, acc[q * 2]);
        acc[q * 2 + 1] = fmaf(a2.y, w2, acc[q * 2 + 1]);
        acc[q * 2]     = fmaf(a3.x, w3, acc[q * 2]);
        acc[q * 2 + 1] = fmaf(a3.y, w3, acc[q * 2 + 1]);
      }
    }
  }

  const float ndv = nd[d];
  const float4 ca0 = *reinterpret_cast<const float4*>(CA + c16 * 8);
  const float4 ca1 = *reinterpret_cast<const float4*>(CA + c16 * 8 + 4);
  const float4 cb0 = *reinterpret_cast<const float4*>(CB + c16 * 8);
  const float4 cb1 = *reinterpret_cast<const float4*>(CB + c16 * 8 + 4);
  float4 o0, o1;
  o0.x = acc[0] * ndv * ca0.x + cb0.x;
  o0.y = acc[1] * ndv * ca0.y + cb0.y;
  o0.z = acc[2] * ndv * ca0.z + cb0.z;
  o0.w = acc[3] * ndv * ca0.w + cb0.w;
  o1.x = acc[4] * ndv * ca1.x + cb1.x;
  o1.y = acc[5] * ndv * ca1.y + cb1.y;
  o1.z = acc[6] * ndv * ca1.z + cb1.z;
  o1.w = acc[7] * ndv * ca1.w + cb1.w;
  *reinterpret_cast<float4*>(outf + (size_t)d * D + c16 * 8) = o0;
  *reinterpret_cast<float4*>(outf + (size_t)d * D + c16 * 8 + 4) = o1;
}

// ---------------- launch ----------------

extern "C" void kernel_launch(void* const* d_in, const int* in_sizes, int n_in,
                              void* d_out, int out_size, void* d_ws, size_t ws_size,
                              hipStream_t stream) {
  const float* x = (const float*)d_in[0];
  const int* esrc = (const int*)d_in[1];
  const int* edst = (const int*)d_in[2];
  const float* W0 = (const float*)d_in[3];
  const float* b0 = (const float*)d_in[4];
  const float* W1 = (const float*)d_in[5];
  const float* b1 = (const float*)d_in[6];
  const float* W2 = (const float*)d_in[7];
  const float* b2 = (const float*)d_in[8];
  const float* g0 = (const float*)d_in[9];
  const float* be0 = (const float*)d_in[10];
  const float* m0 = (const float*)d_in[11];
  const float* v0 = (const float*)d_in[12];
  const float* g1 = (const float*)d_in[13];
  const float* be1 = (const float*)d_in[14];
  const float* m1 = (const float*)d_in[15];
  const float* v1 = (const float*)d_in[16];
  const int N = in_sizes[0] / D;
  const int E = in_sizes[1];

  const int SB = (E + NSL - 1) / NSL;
  const uint Msb = (uint)(((1ULL << 40) + (unsigned long long)SB - 1) / (unsigned long long)SB);

  char* p = (char*)d_ws;
  auto carve = [&](size_t bytes) {
    char* r = p;
    p += (bytes + 255) & ~(size_t)255;
    return (void*)r;
  };
  uint* hs16 = (uint*)carve((size_t)N * 64 * 4);           // f16 ping buffer in ws
  ushort* Wt = (ushort*)carve((size_t)3 * D * D * 2);
  float* CA = (float*)carve((size_t)3 * D * 4);
  float* CB = (float*)carve((size_t)3 * D * 4);
  float* ns = (float*)carve((size_t)N * 4);
  float* nd = (float*)carve((size_t)N * 4);
  uint* pd = (uint*)carve((size_t)NSL * PBU * 4);
  uint* ps = (uint*)carve((size_t)NSL * PBU * 4);
  uchar* rank8 = (uchar*)carve((size_t)E);
  int* totd = (int*)carve((size_t)N * 4);
  int* rofs = (int*)carve((size_t)(N + 1) * 4);
  const int nch = (N + 1023) / 1024;
  int* csum = (int*)carve((size_t)nch * 4);
  int* ticket = (int*)carve(256);
  int* csr = (int*)carve((size_t)E * 4);
  uint* hsOut = (uint*)d_out;  // f16 pong buffer in d_out (fully rewritten at the end)

  hipMemsetAsync(ticket, 0, 4, stream);
  k_build1<<<113, 1024, 0, stream>>>(esrc, edst, W0, W1, W2, b0, b1, b2,
                                     g0, be0, m0, v0, g1, be1, m1, v1,
                                     pd, ps, rank8, Wt, CA, CB, E, SB);
  k_build2s<<<nch, 256, 0, stream>>>(pd, ps, totd, ns, nd, csum, rofs, ticket, N, nch);
  k_scan_final<<<nch, 256, 0, stream>>>(totd, csum, rofs, N);

  const int gb = (N + 127) / 128;
  const int scb = (E + 255) / 256;
  const int fb = (N + 127) / 128;
  const int sb = (N + 15) / 16;
  // layer-0 GEMM (f32 input) + scatter merged
  k_sg<<<gb + scb, 256, 0, stream>>>(x, Wt, ns, (ushort*)hs16, esrc, edst, rank8, pd, rofs,
                                     csr, N, E, Msb, gb);
  // fused: spmm L0 + gemm L1  -> d_out (f16 region)
  k_spgm<<<fb, 256, 0, stream>>>(hs16, csr, rofs, nd, ns, CA, CB, Wt + 16384,
                                 (ushort*)hsOut, N);
  // fused: spmm L1 + gemm L2  -> hs16
  k_spgm<<<fb, 256, 0, stream>>>(hsOut, csr, rofs, nd, ns, CA + D, CB + D, Wt + 32768,
                                 (ushort*)hs16, N);
  // final spmm L2 -> fp32 out
  k_spmm16<<<sb, 256, 0, stream>>>(hs16, csr, rofs, nd, CA + 2 * D, CB + 2 * D,
                                   (float*)d_out, N);
}